// Round 1
// baseline (238.684 us; speedup 1.0000x reference)
//
#include <hip/hip_runtime.h>
#include <hip/hip_bf16.h>
#include <hip/hip_fp16.h>

typedef __attribute__((ext_vector_type(4))) float f32x4;
typedef __attribute__((ext_vector_type(8))) _Float16 f16x8;
typedef __attribute__((ext_vector_type(8))) unsigned short u16x8;

__device__ __forceinline__ unsigned short f2h(float f) {
    _Float16 h = (_Float16)f;
    return __builtin_bit_cast(unsigned short, h);
}

#define GLOAD_LDS16(gp, lp) __builtin_amdgcn_global_load_lds( \
    (const __attribute__((address_space(1))) void*)(gp), \
    (__attribute__((address_space(3))) void*)(lp), 16, 0, 0)

// ---------------- fp32 -> fp16 elementwise convert (vectorized) ----------------
__global__ void cvt_kernel(const float* __restrict__ in, ushort* __restrict__ out, int n4) {
    int stride = gridDim.x * blockDim.x;
    for (int i = blockIdx.x * blockDim.x + threadIdx.x; i < n4; i += stride) {
        float4 v = ((const float4*)in)[i];
        ushort4 o;
        o.x = f2h(v.x); o.y = f2h(v.y); o.z = f2h(v.z); o.w = f2h(v.w);
        ((ushort4*)out)[i] = o;
    }
}

// ---------------- transpose + convert: dst[c][r] = f16(src[r][c]) ----------------
__global__ void transpose_cvt(const float* __restrict__ src, ushort* __restrict__ dst,
                              int R, int C) {
    __shared__ float tile[32][33];
    int tx = threadIdx.x, ty = threadIdx.y;
    int c = blockIdx.x * 32 + tx;
    int r0 = blockIdx.y * 32;
#pragma unroll
    for (int i = ty; i < 32; i += 8) {
        int r = r0 + i;
        tile[i][tx] = (r < R && c < C) ? src[(size_t)r * C + c] : 0.f;
    }
    __syncthreads();
    int rr = r0 + tx;
    int c0 = blockIdx.x * 32;
#pragma unroll
    for (int i = ty; i < 32; i += 8) {
        int cc = c0 + i;
        if (cc < C && rr < R) dst[(size_t)cc * R + rr] = f2h(tile[tx][i]);
    }
}

// ---------------- generic f16 GEMM: C[M,N] = A[M,K] * Bt[N,K]^T (+bias) ----------------
// 128x128 tile, BK=64, 4 waves (2x2), each wave 64x64 via 4x4 frags of 16x16x32.
template<int OUT_F16, int HAS_BIAS>
__global__ __launch_bounds__(256) void gemm_bt(
    const ushort* __restrict__ A, const ushort* __restrict__ Bt,
    void* __restrict__ C, const float* __restrict__ bias,
    int M, int N, int K)
{
    __shared__ ushort As[128 * 64];
    __shared__ ushort Bs[128 * 64];
    const int tid = threadIdx.x;
    const int lane = tid & 63;
    const int w = tid >> 6;
    const int wr = (w >> 1) * 64, wc = (w & 1) * 64;
    const int m0 = blockIdx.x * 128, n0 = blockIdx.y * 128;
    const int l15 = lane & 15, lhi = lane >> 4;

    f32x4 acc[4][4] = {};

    for (int k0 = 0; k0 < K; k0 += 64) {
        __syncthreads();
#pragma unroll
        for (int i = 0; i < 4; ++i) {
            int c = i * 256 + tid;
            int m = m0 + (c >> 3);
            if (m > M - 1) m = M - 1;
            GLOAD_LDS16(A + (size_t)m * K + k0 + (c & 7) * 8, &As[c * 8]);
        }
#pragma unroll
        for (int i = 0; i < 4; ++i) {
            int c = i * 256 + tid;
            GLOAD_LDS16(Bt + (size_t)(n0 + (c >> 3)) * K + k0 + (c & 7) * 8, &Bs[c * 8]);
        }
        __syncthreads();
#pragma unroll
        for (int kk = 0; kk < 2; ++kk) {
            f16x8 af[4], bfr[4];
#pragma unroll
            for (int mi = 0; mi < 4; ++mi)
                af[mi] = *(const f16x8*)&As[(wr + mi * 16 + l15) * 64 + kk * 32 + lhi * 8];
#pragma unroll
            for (int ni = 0; ni < 4; ++ni)
                bfr[ni] = *(const f16x8*)&Bs[(wc + ni * 16 + l15) * 64 + kk * 32 + lhi * 8];
#pragma unroll
            for (int mi = 0; mi < 4; ++mi)
#pragma unroll
                for (int ni = 0; ni < 4; ++ni)
                    acc[mi][ni] = __builtin_amdgcn_mfma_f32_16x16x32_f16(
                        af[mi], bfr[ni], acc[mi][ni], 0, 0, 0);
        }
    }

#pragma unroll
    for (int mi = 0; mi < 4; ++mi)
#pragma unroll
        for (int ni = 0; ni < 4; ++ni)
#pragma unroll
            for (int r = 0; r < 4; ++r) {
                int row = m0 + wr + mi * 16 + lhi * 4 + r;
                int col = n0 + wc + ni * 16 + l15;
                if (row < M) {
                    float v = acc[mi][ni][r];
                    if (HAS_BIAS) v += bias[col];
                    if (OUT_F16) ((ushort*)C)[(size_t)row * N + col] = f2h(v);
                    else         ((float*)C)[(size_t)row * N + col] = v;
                }
            }
}

// ---------------- fused attention for one (b, h, 128-row T tile) ----------------
// Q:[B*T,640] f16, KV:[B*77,1280] f16 (K cols 0..639, V cols 640..1279), O:[B*T,640] f16
__global__ __launch_bounds__(256) void attn_kernel(
    const ushort* __restrict__ Q, const ushort* __restrict__ KV, ushort* __restrict__ O)
{
    __shared__ ushort Qs[128 * 96];  // [t][d]   d padded 80->96
    __shared__ ushort Ks[80 * 96];   // [s][d]   s padded 77->80 (zeros), d padded
    __shared__ ushort Vt[80 * 96];   // [d][s]   s padded 77->96 (zeros)
    __shared__ ushort Ps[128 * 96];  // [t][s]   s padded (zeros)
    const int tid = threadIdx.x;
    const int lane = tid & 63;
    const int w = tid >> 6;
    const int l15 = lane & 15, lhi = lane >> 4;
    const int tt = blockIdx.x, h = blockIdx.y, b = blockIdx.z;
    const int wm = w * 32;

    const size_t qbase = ((size_t)b * 4096 + (size_t)tt * 128) * 640 + h * 80;
    const size_t kvbase = (size_t)b * 77 * 1280 + h * 80;
    const u16x8 z8 = {0, 0, 0, 0, 0, 0, 0, 0};

    // phase 0: stage Q, K; zero Vt, Ps
    for (int i = tid; i < 128 * 12; i += 256) {
        int m = i / 12, c = i % 12;
        u16x8 v = (c < 10) ? *(const u16x8*)(Q + qbase + (size_t)m * 640 + c * 8) : z8;
        *(u16x8*)&Qs[m * 96 + c * 8] = v;
    }
    for (int i = tid; i < 80 * 12; i += 256) {
        int s = i / 12, c = i % 12;
        u16x8 v = (s < 77 && c < 10) ? *(const u16x8*)(KV + kvbase + (size_t)s * 1280 + c * 8) : z8;
        *(u16x8*)&Ks[s * 96 + c * 8] = v;
        *(u16x8*)&Vt[i * 8] = z8;
    }
    for (int i = tid; i < 128 * 12; i += 256) *(u16x8*)&Ps[i * 8] = z8;
    __syncthreads();

    // phase 1: scatter V^T
    for (int i = tid; i < 77 * 80; i += 256) {
        int s = i / 80, d = i % 80;
        Vt[d * 96 + s] = KV[kvbase + (size_t)s * 1280 + 640 + d];
    }
    __syncthreads();

    // phase 2: S = Q K^T  (wave w owns rows wm..wm+31: 2 m-frags x 5 s-frags)
    f32x4 sa[2][5] = {};
#pragma unroll
    for (int kk = 0; kk < 3; ++kk) {
        f16x8 aq[2], bk[5];
#pragma unroll
        for (int mi = 0; mi < 2; ++mi)
            aq[mi] = *(const f16x8*)&Qs[(wm + mi * 16 + l15) * 96 + kk * 32 + lhi * 8];
#pragma unroll
        for (int ni = 0; ni < 5; ++ni)
            bk[ni] = *(const f16x8*)&Ks[(ni * 16 + l15) * 96 + kk * 32 + lhi * 8];
#pragma unroll
        for (int mi = 0; mi < 2; ++mi)
#pragma unroll
            for (int ni = 0; ni < 5; ++ni)
                sa[mi][ni] = __builtin_amdgcn_mfma_f32_16x16x32_f16(aq[mi], bk[ni], sa[mi][ni], 0, 0, 0);
    }

    // softmax over s (77 valid cols), exact, row spread over 16 lanes
    const float sc = 0.1118033988749895f;  // 1/sqrt(80)
#pragma unroll
    for (int mi = 0; mi < 2; ++mi) {
#pragma unroll
        for (int r = 0; r < 4; ++r) {
            int row = wm + mi * 16 + lhi * 4 + r;
            bool v4ok = l15 < 13;  // col 64+l15 < 77
            float v0 = sa[mi][0][r] * sc, v1 = sa[mi][1][r] * sc;
            float v2 = sa[mi][2][r] * sc, v3 = sa[mi][3][r] * sc;
            float v4 = sa[mi][4][r] * sc;
            float mx = fmaxf(fmaxf(v0, v1), fmaxf(v2, v3));
            if (v4ok) mx = fmaxf(mx, v4);
#pragma unroll
            for (int off = 1; off < 16; off <<= 1) mx = fmaxf(mx, __shfl_xor(mx, off, 16));
            float p0 = __expf(v0 - mx), p1 = __expf(v1 - mx);
            float p2 = __expf(v2 - mx), p3 = __expf(v3 - mx);
            float p4 = v4ok ? __expf(v4 - mx) : 0.f;
            float s = p0 + p1 + p2 + p3 + p4;
#pragma unroll
            for (int off = 1; off < 16; off <<= 1) s += __shfl_xor(s, off, 16);
            float inv = 1.f / s;
            Ps[row * 96 + 0 * 16 + l15] = f2h(p0 * inv);
            Ps[row * 96 + 1 * 16 + l15] = f2h(p1 * inv);
            Ps[row * 96 + 2 * 16 + l15] = f2h(p2 * inv);
            Ps[row * 96 + 3 * 16 + l15] = f2h(p3 * inv);
            Ps[row * 96 + 4 * 16 + l15] = f2h(p4 * inv);
        }
    }
    __syncthreads();

    // phase 3: O = P V   (2 m-frags x 5 d-frags, K over s = 3 steps)
    f32x4 oa[2][5] = {};
#pragma unroll
    for (int kk = 0; kk < 3; ++kk) {
        f16x8 ap[2], bv[5];
#pragma unroll
        for (int mi = 0; mi < 2; ++mi)
            ap[mi] = *(const f16x8*)&Ps[(wm + mi * 16 + l15) * 96 + kk * 32 + lhi * 8];
#pragma unroll
        for (int ni = 0; ni < 5; ++ni)
            bv[ni] = *(const f16x8*)&Vt[(ni * 16 + l15) * 96 + kk * 32 + lhi * 8];
#pragma unroll
        for (int mi = 0; mi < 2; ++mi)
#pragma unroll
            for (int ni = 0; ni < 5; ++ni)
                oa[mi][ni] = __builtin_amdgcn_mfma_f32_16x16x32_f16(ap[mi], bv[ni], oa[mi][ni], 0, 0, 0);
    }
#pragma unroll
    for (int mi = 0; mi < 2; ++mi)
#pragma unroll
        for (int ni = 0; ni < 5; ++ni)
#pragma unroll
            for (int r = 0; r < 4; ++r) {
                int row = wm + mi * 16 + lhi * 4 + r;
                int col = ni * 16 + l15;
                O[qbase + (size_t)row * 640 + col] = f2h(oa[mi][ni][r]);
            }
}

extern "C" void kernel_launch(void* const* d_in, const int* in_sizes, int n_in,
                              void* d_out, int out_size, void* d_ws, size_t ws_size,
                              hipStream_t stream) {
    (void)in_sizes; (void)n_in; (void)out_size; (void)ws_size;
    const float* tokens  = (const float*)d_in[0];
    const float* context = (const float*)d_in[1];
    const float* Wq = (const float*)d_in[2];
    const float* Wk = (const float*)d_in[3];
    const float* Wv = (const float*)d_in[4];
    const float* Wo = (const float*)d_in[5];
    const float* bo = (const float*)d_in[6];
    float* out = (float*)d_out;

    ushort* ws    = (ushort*)d_ws;
    ushort* tok16 = ws;                                  // 32768*640
    ushort* ctx16 = tok16 + (size_t)32768 * 640;         // 616*768
    ushort* WqT   = ctx16 + (size_t)616 * 768;           // 640*640 [n][k]
    ushort* WoT   = WqT + (size_t)640 * 640;             // 640*640 [n][k]
    ushort* WkvT  = WoT + (size_t)640 * 640;             // 1280*768 [n][k]
    ushort* Qb    = WkvT + (size_t)1280 * 768;           // 32768*640
    ushort* KVb   = Qb + (size_t)32768 * 640;            // 616*1280
    ushort* CtxO  = tok16;                               // reuse (tokens dead after Q GEMM)

    cvt_kernel<<<4096, 256, 0, stream>>>(tokens, tok16, 32768 * 640 / 4);
    cvt_kernel<<<464, 256, 0, stream>>>(context, ctx16, 616 * 768 / 4);
    transpose_cvt<<<dim3(20, 20), dim3(32, 8), 0, stream>>>(Wq, WqT, 640, 640);
    transpose_cvt<<<dim3(20, 20), dim3(32, 8), 0, stream>>>(Wo, WoT, 640, 640);
    transpose_cvt<<<dim3(20, 24), dim3(32, 8), 0, stream>>>(Wk, WkvT, 768, 640);
    transpose_cvt<<<dim3(20, 24), dim3(32, 8), 0, stream>>>(Wv, WkvT + (size_t)640 * 768, 768, 640);

    gemm_bt<1, 0><<<dim3(256, 5), 256, 0, stream>>>(tok16, WqT, Qb, nullptr, 32768, 640, 640);
    gemm_bt<1, 0><<<dim3(5, 10), 256, 0, stream>>>(ctx16, WkvT, KVb, nullptr, 616, 1280, 768);
    attn_kernel<<<dim3(32, 8, 8), 256, 0, stream>>>(Qb, KVb, CtxO);
    gemm_bt<0, 1><<<dim3(256, 5), 256, 0, stream>>>(CtxO, WoT, out, bo, 32768, 640, 640);
}

// Round 2
// 226.621 us; speedup vs baseline: 1.0532x; 1.0532x over previous
//
#include <hip/hip_runtime.h>
#include <hip/hip_bf16.h>
#include <hip/hip_fp16.h>

typedef __attribute__((ext_vector_type(4))) float f32x4;
typedef __attribute__((ext_vector_type(8))) _Float16 f16x8;
typedef __attribute__((ext_vector_type(8))) unsigned short u16x8;

__device__ __forceinline__ unsigned short f2h(float f) {
    _Float16 h = (_Float16)f;
    return __builtin_bit_cast(unsigned short, h);
}

#define GLOAD_LDS16(gp, lp) __builtin_amdgcn_global_load_lds( \
    (const __attribute__((address_space(1))) void*)(gp), \
    (__attribute__((address_space(3))) void*)(lp), 16, 0, 0)

#define BAR() do { __builtin_amdgcn_sched_barrier(0); \
                   __builtin_amdgcn_s_barrier(); \
                   __builtin_amdgcn_sched_barrier(0); } while (0)
#define WAITLGKM0() do { asm volatile("s_waitcnt lgkmcnt(0)" ::: "memory"); \
                         __builtin_amdgcn_sched_barrier(0); } while (0)
#define WAITVM4() asm volatile("s_waitcnt vmcnt(4)" ::: "memory")
#define PRIO1() __builtin_amdgcn_s_setprio(1)
#define PRIO0() __builtin_amdgcn_s_setprio(0)

// ---------------- fp32 -> fp16 elementwise convert (vectorized) ----------------
__global__ void cvt_kernel(const float* __restrict__ in, ushort* __restrict__ out, int n4) {
    int stride = gridDim.x * blockDim.x;
    for (int i = blockIdx.x * blockDim.x + threadIdx.x; i < n4; i += stride) {
        float4 v = ((const float4*)in)[i];
        ushort4 o;
        o.x = f2h(v.x); o.y = f2h(v.y); o.z = f2h(v.z); o.w = f2h(v.w);
        ((ushort4*)out)[i] = o;
    }
}

// ---------------- transpose + convert: dst[c][r] = f16(src[r][c]) ----------------
__global__ void transpose_cvt(const float* __restrict__ src, ushort* __restrict__ dst,
                              int R, int C) {
    __shared__ float tile[32][33];
    int tx = threadIdx.x, ty = threadIdx.y;
    int c = blockIdx.x * 32 + tx;
    int r0 = blockIdx.y * 32;
#pragma unroll
    for (int i = ty; i < 32; i += 8) {
        int r = r0 + i;
        tile[i][tx] = (r < R && c < C) ? src[(size_t)r * C + c] : 0.f;
    }
    __syncthreads();
    int rr = r0 + tx;
    int c0 = blockIdx.x * 32;
#pragma unroll
    for (int i = ty; i < 32; i += 8) {
        int cc = c0 + i;
        if (cc < C && rr < R) dst[(size_t)cc * R + rr] = f2h(tile[tx][i]);
    }
}

// ================= 256x256 8-phase f16 GEMM: C[M,N] = A[M,K] * Bt[N,K]^T =================
// BM=BN=256, BK=64, 512 threads = 8 waves (2M x 4N), per-wave 128x64 output.
// LDS 128KB: A/B double-buffered K-tiles. XOR-swizzled LDS (slot ^= row&7, 16B slots),
// linear gload_lds dest + pre-swizzled global source. Counted vmcnt(4) at phases 4/8.
// Requires: K % 128 == 0 (even number of 64-wide K-tiles), M,N arbitrary (clamped/masked).
template<int OUT_F16, int HAS_BIAS>
__global__ __launch_bounds__(512, 2) void gemm8p(
    const ushort* __restrict__ A, const ushort* __restrict__ Bt,
    void* __restrict__ C, const float* __restrict__ bias,
    int M, int N, int K)
{
    __shared__ __align__(16) ushort lds[65536];  // 128 KiB
    // ushort offsets: A-tile buf0 = 0, buf1 = 16384; B-tile buf0 = 32768, buf1 = 49152.
    // within a tile: row*64 + slot*8 (slot = 16B unit), half h at +h*8192.
    const int tid = threadIdx.x;
    const int lane = tid & 63;
    const int w = tid >> 6;
    const int wm = (w >> 2) * 128;
    const int wn = (w & 3) * 64;
    const int l15 = lane & 15, lhi = lane >> 4;
    const int axor = l15 & 7;
    const int m0 = blockIdx.x * 256, n0 = blockIdx.y * 256;
    const int NT = K >> 6, NJ = NT >> 1;
    // staging: thread handles 16B slots u=tid and u=tid+512 of a 128-row half (1024 slots)
    const int rowU = tid >> 3;                        // 0..63 (second seg: +64)
    const int colU = ((tid & 7) ^ (rowU & 7)) * 8;    // pre-swizzled global col (elems)

    f32x4 acc[8][4] = {};
    f16x8 aR[2][4], bR0[2][2], bR1[2][2];

#define STAGE(PTR, RB, RMAX, KK0, LB) do { \
    int r0_ = (RB) + rowU; int r1_ = r0_ + 64; \
    r0_ = r0_ < (RMAX) ? r0_ : (RMAX) - 1; \
    r1_ = r1_ < (RMAX) ? r1_ : (RMAX) - 1; \
    GLOAD_LDS16((PTR) + (size_t)r0_ * K + (KK0) + colU, &lds[(LB) + tid * 8]); \
    GLOAD_LDS16((PTR) + (size_t)r1_ * K + (KK0) + colU, &lds[(LB) + 4096 + tid * 8]); \
} while (0)

#define READA(MH, BASE) do { \
    _Pragma("unroll") for (int kk = 0; kk < 2; ++kk) \
    _Pragma("unroll") for (int mi = 0; mi < 4; ++mi) \
        aR[kk][mi] = *(const f16x8*)&lds[(BASE) + (wm + (MH)*64 + mi*16 + l15)*64 + (((kk*4 + lhi) ^ axor) * 8)]; \
} while (0)

#define READB(NH, BASE, BR) do { \
    _Pragma("unroll") for (int kk = 0; kk < 2; ++kk) \
    _Pragma("unroll") for (int ni = 0; ni < 2; ++ni) \
        (BR)[kk][ni] = *(const f16x8*)&lds[(BASE) + (wn + (NH)*32 + ni*16 + l15)*64 + (((kk*4 + lhi) ^ axor) * 8)]; \
} while (0)

#define MFMAQ(MH, NH, BR) do { \
    _Pragma("unroll") for (int kk = 0; kk < 2; ++kk) \
    _Pragma("unroll") for (int mi = 0; mi < 4; ++mi) \
    _Pragma("unroll") for (int ni = 0; ni < 2; ++ni) \
        acc[(MH)*4 + mi][(NH)*2 + ni] = __builtin_amdgcn_mfma_f32_16x16x32_f16( \
            aR[kk][mi], (BR)[kk][ni], acc[(MH)*4 + mi][(NH)*2 + ni], 0, 0, 0); \
} while (0)

    // ---- prologue: tile0 (A+B) and tile1 (B only); tile1's A staged in ph1/ph2 ----
    STAGE(A,  m0,       M, 0,  0);            // A(0).h0
    STAGE(A,  m0 + 128, M, 0,  8192);         // A(0).h1
    STAGE(Bt, n0,       N, 0,  32768);        // B(0).h0
    STAGE(Bt, n0 + 128, N, 0,  32768 + 8192); // B(0).h1
    STAGE(Bt, n0,       N, 64, 49152);        // B(1).h0
    STAGE(Bt, n0 + 128, N, 64, 49152 + 8192); // B(1).h1
    WAITVM4();  // tile0's 8 loads complete; B(1)'s 4 in flight
    BAR();

    for (int j = 0; j < NJ; ++j) {
        const int k1 = (2*j + 1) << 6;
        const int tn0 = (2*j + 2 < NT) ? (2*j + 2) : (NT - 1);
        const int tn1 = (2*j + 3 < NT) ? (2*j + 3) : (NT - 1);
        const int kn0 = tn0 << 6, kn1 = tn1 << 6;

        // ph1: tile t0 from buf0, quadrant (mh0,nh0); stage A(t1).h0
        READA(0, 0); READB(0, 32768, bR0);
        STAGE(A, m0, M, k1, 16384);
        BAR(); WAITLGKM0(); PRIO1(); MFMAQ(0, 0, bR0); PRIO0(); BAR();
        // ph2: quadrant (mh0,nh1); stage A(t1).h1
        READB(1, 32768, bR1);
        STAGE(A, m0 + 128, M, k1, 16384 + 8192);
        BAR(); WAITLGKM0(); PRIO1(); MFMAQ(0, 1, bR1); PRIO0(); BAR();
        // ph3: quadrant (mh1,nh0); stage B(t0+2).h0
        READA(1, 0);
        STAGE(Bt, n0, N, kn0, 32768);
        BAR(); WAITLGKM0(); PRIO1(); MFMAQ(1, 0, bR0); PRIO0(); BAR();
        // ph4: quadrant (mh1,nh1); stage B(t0+2).h1; counted vmcnt
        STAGE(Bt, n0 + 128, N, kn0, 32768 + 8192);
        BAR(); PRIO1(); MFMAQ(1, 1, bR1); PRIO0(); WAITVM4(); BAR();
        // ph5: tile t1 from buf1, quadrant (mh0,nh0); stage A(t0+2).h0
        READA(0, 16384); READB(0, 49152, bR0);
        STAGE(A, m0, M, kn0, 0);
        BAR(); WAITLGKM0(); PRIO1(); MFMAQ(0, 0, bR0); PRIO0(); BAR();
        // ph6: quadrant (mh0,nh1); stage A(t0+2).h1
        READB(1, 49152, bR1);
        STAGE(A, m0 + 128, M, kn0, 8192);
        BAR(); WAITLGKM0(); PRIO1(); MFMAQ(0, 1, bR1); PRIO0(); BAR();
        // ph7: quadrant (mh1,nh0); stage B(t1+2).h0
        READA(1, 16384);
        STAGE(Bt, n0, N, kn1, 49152);
        BAR(); WAITLGKM0(); PRIO1(); MFMAQ(1, 0, bR0); PRIO0(); BAR();
        // ph8: quadrant (mh1,nh1); stage B(t1+2).h1; counted vmcnt
        STAGE(Bt, n0 + 128, N, kn1, 49152 + 8192);
        BAR(); PRIO1(); MFMAQ(1, 1, bR1); PRIO0(); WAITVM4(); BAR();
    }

    // ---- epilogue: C write (mask rows vs M, cols vs N) ----
#pragma unroll
    for (int mf = 0; mf < 8; ++mf) {
        int row = m0 + wm + (mf >> 2) * 64 + (mf & 3) * 16 + lhi * 4;
#pragma unroll
        for (int nf = 0; nf < 4; ++nf) {
            int col = n0 + wn + (nf >> 1) * 32 + (nf & 1) * 16 + l15;
            if (col < N) {
#pragma unroll
                for (int r = 0; r < 4; ++r) {
                    if (row + r < M) {
                        float v = acc[mf][nf][r];
                        if (HAS_BIAS) v += bias[col];
                        if (OUT_F16) ((ushort*)C)[(size_t)(row + r) * N + col] = f2h(v);
                        else         ((float*)C)[(size_t)(row + r) * N + col] = v;
                    }
                }
            }
        }
    }
#undef STAGE
#undef READA
#undef READB
#undef MFMAQ
}

// ---------------- small 128x128 GEMM (kept for the tiny KV projection) ----------------
template<int OUT_F16, int HAS_BIAS>
__global__ __launch_bounds__(256) void gemm_bt(
    const ushort* __restrict__ A, const ushort* __restrict__ Bt,
    void* __restrict__ C, const float* __restrict__ bias,
    int M, int N, int K)
{
    __shared__ ushort As[128 * 64];
    __shared__ ushort Bs[128 * 64];
    const int tid = threadIdx.x;
    const int lane = tid & 63;
    const int w = tid >> 6;
    const int wr = (w >> 1) * 64, wc = (w & 1) * 64;
    const int m0 = blockIdx.x * 128, n0 = blockIdx.y * 128;
    const int l15 = lane & 15, lhi = lane >> 4;

    f32x4 acc[4][4] = {};

    for (int k0 = 0; k0 < K; k0 += 64) {
        __syncthreads();
#pragma unroll
        for (int i = 0; i < 4; ++i) {
            int c = i * 256 + tid;
            int m = m0 + (c >> 3);
            if (m > M - 1) m = M - 1;
            GLOAD_LDS16(A + (size_t)m * K + k0 + (c & 7) * 8, &As[c * 8]);
        }
#pragma unroll
        for (int i = 0; i < 4; ++i) {
            int c = i * 256 + tid;
            GLOAD_LDS16(Bt + (size_t)(n0 + (c >> 3)) * K + k0 + (c & 7) * 8, &Bs[c * 8]);
        }
        __syncthreads();
#pragma unroll
        for (int kk = 0; kk < 2; ++kk) {
            f16x8 af[4], bfr[4];
#pragma unroll
            for (int mi = 0; mi < 4; ++mi)
                af[mi] = *(const f16x8*)&As[(wr + mi * 16 + l15) * 64 + kk * 32 + lhi * 8];
#pragma unroll
            for (int ni = 0; ni < 4; ++ni)
                bfr[ni] = *(const f16x8*)&Bs[(wc + ni * 16 + l15) * 64 + kk * 32 + lhi * 8];
#pragma unroll
            for (int mi = 0; mi < 4; ++mi)
#pragma unroll
                for (int ni = 0; ni < 4; ++ni)
                    acc[mi][ni] = __builtin_amdgcn_mfma_f32_16x16x32_f16(
                        af[mi], bfr[ni], acc[mi][ni], 0, 0, 0);
        }
    }

#pragma unroll
    for (int mi = 0; mi < 4; ++mi)
#pragma unroll
        for (int ni = 0; ni < 4; ++ni)
#pragma unroll
            for (int r = 0; r < 4; ++r) {
                int row = m0 + wr + mi * 16 + lhi * 4 + r;
                int col = n0 + wc + ni * 16 + l15;
                if (row < M) {
                    float v = acc[mi][ni][r];
                    if (HAS_BIAS) v += bias[col];
                    if (OUT_F16) ((ushort*)C)[(size_t)row * N + col] = f2h(v);
                    else         ((float*)C)[(size_t)row * N + col] = v;
                }
            }
}

// ---------------- fused attention for one (b, h, 128-row T tile) ----------------
// Q:[B*T,640] f16, KV:[B*77,1280] f16 (K cols 0..639, V cols 640..1279), O:[B*T,640] f16
__global__ __launch_bounds__(256) void attn_kernel(
    const ushort* __restrict__ Q, const ushort* __restrict__ KV, ushort* __restrict__ O)
{
    __shared__ ushort Qs[128 * 96];  // [t][d]   d padded 80->96
    __shared__ ushort Ks[80 * 96];   // [s][d]   s padded 77->80 (zeros), d padded
    __shared__ ushort Vt[80 * 96];   // [d][s]   s padded 77->96 (zeros)
    __shared__ ushort Ps[128 * 96];  // [t][s]   s padded (zeros)
    const int tid = threadIdx.x;
    const int lane = tid & 63;
    const int w = tid >> 6;
    const int l15 = lane & 15, lhi = lane >> 4;
    const int tt = blockIdx.x, h = blockIdx.y, b = blockIdx.z;
    const int wm = w * 32;

    const size_t qbase = ((size_t)b * 4096 + (size_t)tt * 128) * 640 + h * 80;
    const size_t kvbase = (size_t)b * 77 * 1280 + h * 80;
    const u16x8 z8 = {0, 0, 0, 0, 0, 0, 0, 0};

    // phase 0: stage Q, K; zero Vt, Ps
    for (int i = tid; i < 128 * 12; i += 256) {
        int m = i / 12, c = i % 12;
        u16x8 v = (c < 10) ? *(const u16x8*)(Q + qbase + (size_t)m * 640 + c * 8) : z8;
        *(u16x8*)&Qs[m * 96 + c * 8] = v;
    }
    for (int i = tid; i < 80 * 12; i += 256) {
        int s = i / 12, c = i % 12;
        u16x8 v = (s < 77 && c < 10) ? *(const u16x8*)(KV + kvbase + (size_t)s * 1280 + c * 8) : z8;
        *(u16x8*)&Ks[s * 96 + c * 8] = v;
        *(u16x8*)&Vt[i * 8] = z8;
    }
    for (int i = tid; i < 128 * 12; i += 256) *(u16x8*)&Ps[i * 8] = z8;
    __syncthreads();

    // phase 1: scatter V^T
    for (int i = tid; i < 77 * 80; i += 256) {
        int s = i / 80, d = i % 80;
        Vt[d * 96 + s] = KV[kvbase + (size_t)s * 1280 + 640 + d];
    }
    __syncthreads();

    // phase 2: S = Q K^T  (wave w owns rows wm..wm+31: 2 m-frags x 5 s-frags)
    f32x4 sa[2][5] = {};
#pragma unroll
    for (int kk = 0; kk < 3; ++kk) {
        f16x8 aq[2], bk[5];
#pragma unroll
        for (int mi = 0; mi < 2; ++mi)
            aq[mi] = *(const f16x8*)&Qs[(wm + mi * 16 + l15) * 96 + kk * 32 + lhi * 8];
#pragma unroll
        for (int ni = 0; ni < 5; ++ni)
            bk[ni] = *(const f16x8*)&Ks[(ni * 16 + l15) * 96 + kk * 32 + lhi * 8];
#pragma unroll
        for (int mi = 0; mi < 2; ++mi)
#pragma unroll
            for (int ni = 0; ni < 5; ++ni)
                sa[mi][ni] = __builtin_amdgcn_mfma_f32_16x16x32_f16(aq[mi], bk[ni], sa[mi][ni], 0, 0, 0);
    }

    // softmax over s (77 valid cols), exact, row spread over 16 lanes
    const float sc = 0.1118033988749895f;  // 1/sqrt(80)
#pragma unroll
    for (int mi = 0; mi < 2; ++mi) {
#pragma unroll
        for (int r = 0; r < 4; ++r) {
            int row = wm + mi * 16 + lhi * 4 + r;
            bool v4ok = l15 < 13;  // col 64+l15 < 77
            float v0 = sa[mi][0][r] * sc, v1 = sa[mi][1][r] * sc;
            float v2 = sa[mi][2][r] * sc, v3 = sa[mi][3][r] * sc;
            float v4 = sa[mi][4][r] * sc;
            float mx = fmaxf(fmaxf(v0, v1), fmaxf(v2, v3));
            if (v4ok) mx = fmaxf(mx, v4);
#pragma unroll
            for (int off = 1; off < 16; off <<= 1) mx = fmaxf(mx, __shfl_xor(mx, off, 16));
            float p0 = __expf(v0 - mx), p1 = __expf(v1 - mx);
            float p2 = __expf(v2 - mx), p3 = __expf(v3 - mx);
            float p4 = v4ok ? __expf(v4 - mx) : 0.f;
            float s = p0 + p1 + p2 + p3 + p4;
#pragma unroll
            for (int off = 1; off < 16; off <<= 1) s += __shfl_xor(s, off, 16);
            float inv = 1.f / s;
            Ps[row * 96 + 0 * 16 + l15] = f2h(p0 * inv);
            Ps[row * 96 + 1 * 16 + l15] = f2h(p1 * inv);
            Ps[row * 96 + 2 * 16 + l15] = f2h(p2 * inv);
            Ps[row * 96 + 3 * 16 + l15] = f2h(p3 * inv);
            Ps[row * 96 + 4 * 16 + l15] = f2h(p4 * inv);
        }
    }
    __syncthreads();

    // phase 3: O = P V   (2 m-frags x 5 d-frags, K over s = 3 steps)
    f32x4 oa[2][5] = {};
#pragma unroll
    for (int kk = 0; kk < 3; ++kk) {
        f16x8 ap[2], bv[5];
#pragma unroll
        for (int mi = 0; mi < 2; ++mi)
            ap[mi] = *(const f16x8*)&Ps[(wm + mi * 16 + l15) * 96 + kk * 32 + lhi * 8];
#pragma unroll
        for (int ni = 0; ni < 5; ++ni)
            bv[ni] = *(const f16x8*)&Vt[(ni * 16 + l15) * 96 + kk * 32 + lhi * 8];
#pragma unroll
        for (int mi = 0; mi < 2; ++mi)
#pragma unroll
            for (int ni = 0; ni < 5; ++ni)
                oa[mi][ni] = __builtin_amdgcn_mfma_f32_16x16x32_f16(ap[mi], bv[ni], oa[mi][ni], 0, 0, 0);
    }
#pragma unroll
    for (int mi = 0; mi < 2; ++mi)
#pragma unroll
        for (int ni = 0; ni < 5; ++ni)
#pragma unroll
            for (int r = 0; r < 4; ++r) {
                int row = wm + mi * 16 + lhi * 4 + r;
                int col = ni * 16 + l15;
                O[qbase + (size_t)row * 640 + col] = f2h(oa[mi][ni][r]);
            }
}

extern "C" void kernel_launch(void* const* d_in, const int* in_sizes, int n_in,
                              void* d_out, int out_size, void* d_ws, size_t ws_size,
                              hipStream_t stream) {
    (void)in_sizes; (void)n_in; (void)out_size; (void)ws_size;
    const float* tokens  = (const float*)d_in[0];
    const float* context = (const float*)d_in[1];
    const float* Wq = (const float*)d_in[2];
    const float* Wk = (const float*)d_in[3];
    const float* Wv = (const float*)d_in[4];
    const float* Wo = (const float*)d_in[5];
    const float* bo = (const float*)d_in[6];
    float* out = (float*)d_out;

    ushort* ws    = (ushort*)d_ws;
    ushort* tok16 = ws;                                  // 32768*640
    ushort* ctx16 = tok16 + (size_t)32768 * 640;         // 616*768
    ushort* WqT   = ctx16 + (size_t)616 * 768;           // 640*640 [n][k]
    ushort* WoT   = WqT + (size_t)640 * 640;             // 640*640 [n][k]
    ushort* WkvT  = WoT + (size_t)640 * 640;             // 1280*768 [n][k]
    ushort* Qb    = WkvT + (size_t)1280 * 768;           // 32768*640
    ushort* KVb   = Qb + (size_t)32768 * 640;            // 616*1280
    ushort* CtxO  = tok16;                               // reuse (tokens dead after Q GEMM)

    cvt_kernel<<<4096, 256, 0, stream>>>(tokens, tok16, 32768 * 640 / 4);
    cvt_kernel<<<464, 256, 0, stream>>>(context, ctx16, 616 * 768 / 4);
    transpose_cvt<<<dim3(20, 20), dim3(32, 8), 0, stream>>>(Wq, WqT, 640, 640);
    transpose_cvt<<<dim3(20, 20), dim3(32, 8), 0, stream>>>(Wo, WoT, 640, 640);
    transpose_cvt<<<dim3(20, 24), dim3(32, 8), 0, stream>>>(Wk, WkvT, 768, 640);
    transpose_cvt<<<dim3(20, 24), dim3(32, 8), 0, stream>>>(Wv, WkvT + (size_t)640 * 768, 768, 640);

    // Q = tok16 @ WqT^T : M=32768, N=640, K=640 (NT=10, even)
    gemm8p<1, 0><<<dim3(128, 3), 512, 0, stream>>>(tok16, WqT, Qb, nullptr, 32768, 640, 640);
    // KV projection: tiny (616x1280x768) — keep 128^2 kernel
    gemm_bt<1, 0><<<dim3(5, 10), 256, 0, stream>>>(ctx16, WkvT, KVb, nullptr, 616, 1280, 768);
    attn_kernel<<<dim3(32, 8, 8), 256, 0, stream>>>(Qb, KVb, CtxO);
    // out = CtxO @ WoT^T + bo : M=32768, N=640, K=640
    gemm8p<0, 1><<<dim3(128, 3), 512, 0, stream>>>(CtxO, WoT, out, bo, 32768, 640, 640);
}

// Round 3
// 176.914 us; speedup vs baseline: 1.3492x; 1.2810x over previous
//
#include <hip/hip_runtime.h>
#include <hip/hip_bf16.h>
#include <hip/hip_fp16.h>

typedef __attribute__((ext_vector_type(4))) float f32x4;
typedef __attribute__((ext_vector_type(8))) _Float16 f16x8;
typedef __attribute__((ext_vector_type(8))) unsigned short u16x8;

__device__ __forceinline__ unsigned short f2h(float f) {
    _Float16 h = (_Float16)f;
    return __builtin_bit_cast(unsigned short, h);
}

#define GLOAD_LDS16(gp, lp) __builtin_amdgcn_global_load_lds( \
    (const __attribute__((address_space(1))) void*)(gp), \
    (__attribute__((address_space(3))) void*)(lp), 16, 0, 0)

// ---------------- fp32 -> fp16 elementwise convert (vectorized) ----------------
__global__ void cvt_kernel(const float* __restrict__ in, ushort* __restrict__ out, int n4) {
    int stride = gridDim.x * blockDim.x;
    for (int i = blockIdx.x * blockDim.x + threadIdx.x; i < n4; i += stride) {
        float4 v = ((const float4*)in)[i];
        ushort4 o;
        o.x = f2h(v.x); o.y = f2h(v.y); o.z = f2h(v.z); o.w = f2h(v.w);
        ((ushort4*)out)[i] = o;
    }
}

// ---------------- transpose + convert: dst[c][r] = f16(src[r][c]) ----------------
__global__ void transpose_cvt(const float* __restrict__ src, ushort* __restrict__ dst,
                              int R, int C) {
    __shared__ float tile[32][33];
    int tx = threadIdx.x, ty = threadIdx.y;
    int c = blockIdx.x * 32 + tx;
    int r0 = blockIdx.y * 32;
#pragma unroll
    for (int i = ty; i < 32; i += 8) {
        int r = r0 + i;
        tile[i][tx] = (r < R && c < C) ? src[(size_t)r * C + c] : 0.f;
    }
    __syncthreads();
    int rr = r0 + tx;
    int c0 = blockIdx.x * 32;
#pragma unroll
    for (int i = ty; i < 32; i += 8) {
        int cc = c0 + i;
        if (cc < C && rr < R) dst[(size_t)cc * R + rr] = f2h(tile[tx][i]);
    }
}

// ---------------- 128x128 GEMM (for the tiny KV projection) ----------------
template<int OUT_F16, int HAS_BIAS>
__global__ __launch_bounds__(256) void gemm_bt(
    const ushort* __restrict__ A, const ushort* __restrict__ Bt,
    void* __restrict__ C, const float* __restrict__ bias,
    int M, int N, int K)
{
    __shared__ ushort As[128 * 64];
    __shared__ ushort Bs[128 * 64];
    const int tid = threadIdx.x;
    const int lane = tid & 63;
    const int w = tid >> 6;
    const int wr = (w >> 1) * 64, wc = (w & 1) * 64;
    const int m0 = blockIdx.x * 128, n0 = blockIdx.y * 128;
    const int l15 = lane & 15, lhi = lane >> 4;

    f32x4 acc[4][4] = {};

    for (int k0 = 0; k0 < K; k0 += 64) {
        __syncthreads();
#pragma unroll
        for (int i = 0; i < 4; ++i) {
            int c = i * 256 + tid;
            int m = m0 + (c >> 3);
            if (m > M - 1) m = M - 1;
            GLOAD_LDS16(A + (size_t)m * K + k0 + (c & 7) * 8, &As[c * 8]);
        }
#pragma unroll
        for (int i = 0; i < 4; ++i) {
            int c = i * 256 + tid;
            GLOAD_LDS16(Bt + (size_t)(n0 + (c >> 3)) * K + k0 + (c & 7) * 8, &Bs[c * 8]);
        }
        __syncthreads();
#pragma unroll
        for (int kk = 0; kk < 2; ++kk) {
            f16x8 af[4], bfr[4];
#pragma unroll
            for (int mi = 0; mi < 4; ++mi)
                af[mi] = *(const f16x8*)&As[(wr + mi * 16 + l15) * 64 + kk * 32 + lhi * 8];
#pragma unroll
            for (int ni = 0; ni < 4; ++ni)
                bfr[ni] = *(const f16x8*)&Bs[(wc + ni * 16 + l15) * 64 + kk * 32 + lhi * 8];
#pragma unroll
            for (int mi = 0; mi < 4; ++mi)
#pragma unroll
                for (int ni = 0; ni < 4; ++ni)
                    acc[mi][ni] = __builtin_amdgcn_mfma_f32_16x16x32_f16(
                        af[mi], bfr[ni], acc[mi][ni], 0, 0, 0);
        }
    }

#pragma unroll
    for (int mi = 0; mi < 4; ++mi)
#pragma unroll
        for (int ni = 0; ni < 4; ++ni)
#pragma unroll
            for (int r = 0; r < 4; ++r) {
                int row = m0 + wr + mi * 16 + lhi * 4 + r;
                int col = n0 + wc + ni * 16 + l15;
                if (row < M) {
                    float v = acc[mi][ni][r];
                    if (HAS_BIAS) v += bias[col];
                    if (OUT_F16) ((ushort*)C)[(size_t)row * N + col] = f2h(v);
                    else         ((float*)C)[(size_t)row * N + col] = v;
                }
            }
}

// ---------------- build V^T: Vt[b][h][d=80][s=96] = V[b][s][h*80+d], zero-pad s>=77 ----------------
__global__ void vtrans_kernel(const ushort* __restrict__ KVb, ushort* __restrict__ Vt) {
    int bh = blockIdx.x;        // b*8 + h
    int b = bh >> 3, h = bh & 7;
    for (int idx = threadIdx.x; idx < 80 * 96; idx += 256) {
        int d = idx / 96, s = idx % 96;
        ushort v = 0;
        if (s < 77) v = KVb[((size_t)b * 77 + s) * 1280 + 640 + h * 80 + d];
        Vt[(size_t)bh * 7680 + idx] = v;
    }
}

// ================= fused: tokens->Q-proj->attention->O-proj->out =================
// grid (64 tt, 8 b), 512 threads = 8 waves; wave w handles head w.
// LDS: bufA/bufB = tokens k-chunk dbuf [64][64] f16 swizzled @ 0 / 4096 (ushorts);
//      Qall/Ps   = per-wave [64][104] @ 8192 + w*6656 (aliases nothing live);
//      ctxall    = [64][648] @ 0 (after barrier, aliases bufs + low Qall regions).
__global__ __launch_bounds__(512, 2) void fused_attn(
    const float* __restrict__ tokens, const ushort* __restrict__ WqT,
    const ushort* __restrict__ KVb, const ushort* __restrict__ Vt_g,
    const ushort* __restrict__ WoT, const float* __restrict__ bo,
    float* __restrict__ out)
{
    __shared__ __align__(16) ushort lds[61440];   // 120 KiB
    const int tid = threadIdx.x;
    const int lane = tid & 63;
    const int w = tid >> 6;
    const int l15 = lane & 15, lhi = lane >> 4;
    const int tt = blockIdx.x, b = blockIdx.y;
    const size_t rowbase = (size_t)b * 4096 + (size_t)tt * 64;

    // staging indices: each thread stages one 8-f32 group per 64x64 chunk
    const int srow = tid >> 3;            // 0..63
    const int sc8  = tid & 7;             // slot 0..7
    const int sphys = sc8 ^ (srow & 7);   // swizzled slot

    // ---- prologue: stage tokens chunk 0 into bufA ----
    {
        const float4* sp = (const float4*)(tokens + (rowbase + srow) * 640 + sc8 * 8);
        float4 v0 = sp[0], v1 = sp[1];
        u16x8 o;
        o[0]=f2h(v0.x); o[1]=f2h(v0.y); o[2]=f2h(v0.z); o[3]=f2h(v0.w);
        o[4]=f2h(v1.x); o[5]=f2h(v1.y); o[6]=f2h(v1.z); o[7]=f2h(v1.w);
        *(u16x8*)&lds[srow * 64 + sphys * 8] = o;
    }
    const ushort* Wrow = WqT + (size_t)(w * 80) * 640;
    f16x8 BbE[10], BbO[10];
#pragma unroll
    for (int ni = 0; ni < 5; ++ni)
#pragma unroll
        for (int kk = 0; kk < 2; ++kk)
            BbE[ni*2+kk] = *(const f16x8*)(Wrow + (size_t)(ni*16 + l15) * 640 + kk*32 + lhi*8);
    __syncthreads();

    // ---- Q projection: qacc[4][5] = tokens_tile(64x640) @ Wq[:, w*80..+80] ----
    f32x4 qacc[4][5] = {};
#define QSTEP(BCUR, BNXT, KT, CURB, NXTB) do { \
    float4 s0_, s1_; \
    const int kt_ = (KT); \
    if (kt_ < 9) { \
        const float4* sp_ = (const float4*)(tokens + (rowbase + srow) * 640 + (kt_+1)*64 + sc8*8); \
        s0_ = sp_[0]; s1_ = sp_[1]; \
        _Pragma("unroll") for (int ni = 0; ni < 5; ++ni) \
        _Pragma("unroll") for (int kk = 0; kk < 2; ++kk) \
            (BNXT)[ni*2+kk] = *(const f16x8*)(Wrow + (size_t)(ni*16+l15)*640 + (kt_+1)*64 + kk*32 + lhi*8); \
    } \
    _Pragma("unroll") for (int kk = 0; kk < 2; ++kk) { \
        f16x8 af[4]; \
        _Pragma("unroll") for (int mi = 0; mi < 4; ++mi) { \
            int row_ = mi*16 + l15; \
            af[mi] = *(const f16x8*)&lds[(CURB) + row_*64 + (((kk*4 + lhi) ^ (row_ & 7)))*8]; \
        } \
        _Pragma("unroll") for (int mi = 0; mi < 4; ++mi) \
        _Pragma("unroll") for (int ni = 0; ni < 5; ++ni) \
            qacc[mi][ni] = __builtin_amdgcn_mfma_f32_16x16x32_f16(af[mi], (BCUR)[ni*2+kk], qacc[mi][ni], 0, 0, 0); \
    } \
    if (kt_ < 9) { \
        u16x8 o_; \
        o_[0]=f2h(s0_.x); o_[1]=f2h(s0_.y); o_[2]=f2h(s0_.z); o_[3]=f2h(s0_.w); \
        o_[4]=f2h(s1_.x); o_[5]=f2h(s1_.y); o_[6]=f2h(s1_.z); o_[7]=f2h(s1_.w); \
        *(u16x8*)&lds[(NXTB) + srow*64 + sphys*8] = o_; \
    } \
    __syncthreads(); \
} while (0)

    for (int kp = 0; kp < 5; ++kp) {
        QSTEP(BbE, BbO, 2*kp,     0,    4096);
        QSTEP(BbO, BbE, 2*kp + 1, 4096, 0);
    }
#undef QSTEP

    // ---- write Q f16 into Qall[w] ([64][104], pad cols 80..103 = 0) ----
    const int qoff = 8192 + w * 6656;
#pragma unroll
    for (int mi = 0; mi < 4; ++mi)
#pragma unroll
        for (int ni = 0; ni < 5; ++ni)
#pragma unroll
            for (int r = 0; r < 4; ++r)
                lds[qoff + (mi*16 + lhi*4 + r)*104 + ni*16 + l15] = f2h(qacc[mi][ni][r]);
    for (int idx = lane; idx < 64 * 24; idx += 64) {
        int row = idx / 24, c = 80 + idx % 24;
        lds[qoff + row*104 + c] = 0;
    }
    __builtin_amdgcn_sched_barrier(0);

    // ---- S = Q K^T (per-wave, K frags from L2, rows clamped for s>=77) ----
    f32x4 sa[4][5] = {};
    {
        f16x8 bk[15];
        const ushort* Kbase = KVb + (size_t)b * 77 * 1280 + w * 80;
#pragma unroll
        for (int ni = 0; ni < 5; ++ni) {
            int s = ni*16 + l15;
            int sr = s < 77 ? s : 76;
#pragma unroll
            for (int kk = 0; kk < 3; ++kk)
                bk[ni*3+kk] = *(const f16x8*)(Kbase + (size_t)sr * 1280 + kk*32 + lhi*8);
        }
#pragma unroll
        for (int kk = 0; kk < 3; ++kk) {
            f16x8 aq[4];
#pragma unroll
            for (int mi = 0; mi < 4; ++mi)
                aq[mi] = *(const f16x8*)&lds[qoff + (mi*16 + l15)*104 + kk*32 + lhi*8];
#pragma unroll
            for (int mi = 0; mi < 4; ++mi)
#pragma unroll
                for (int ni = 0; ni < 5; ++ni)
                    sa[mi][ni] = __builtin_amdgcn_mfma_f32_16x16x32_f16(aq[mi], bk[ni*3+kk], sa[mi][ni], 0, 0, 0);
        }
    }
    __builtin_amdgcn_sched_barrier(0);

    // ---- softmax over s (77 valid), store P f16 into Qall[w] region (reuse) ----
    const float sc = 0.11180339887498949f;   // 1/sqrt(80)
#pragma unroll
    for (int mi = 0; mi < 4; ++mi)
#pragma unroll
        for (int r = 0; r < 4; ++r) {
            float v0 = sa[mi][0][r]*sc, v1 = sa[mi][1][r]*sc, v2 = sa[mi][2][r]*sc,
                  v3 = sa[mi][3][r]*sc, v4 = sa[mi][4][r]*sc;
            bool ok4 = l15 < 13;             // col 64+l15 < 77
            float mx = fmaxf(fmaxf(v0, v1), fmaxf(v2, v3));
            if (ok4) mx = fmaxf(mx, v4);
#pragma unroll
            for (int off = 1; off < 16; off <<= 1) mx = fmaxf(mx, __shfl_xor(mx, off, 16));
            float p0 = __expf(v0-mx), p1 = __expf(v1-mx), p2 = __expf(v2-mx), p3 = __expf(v3-mx);
            float p4 = ok4 ? __expf(v4-mx) : 0.f;
            float sm = p0+p1+p2+p3+p4;
#pragma unroll
            for (int off = 1; off < 16; off <<= 1) sm += __shfl_xor(sm, off, 16);
            float inv = 1.f / sm;
            int row = mi*16 + lhi*4 + r;
            lds[qoff + row*104 + 0*16 + l15] = f2h(p0*inv);
            lds[qoff + row*104 + 1*16 + l15] = f2h(p1*inv);
            lds[qoff + row*104 + 2*16 + l15] = f2h(p2*inv);
            lds[qoff + row*104 + 3*16 + l15] = f2h(p3*inv);
            lds[qoff + row*104 + 4*16 + l15] = f2h(p4*inv);
        }
    __builtin_amdgcn_sched_barrier(0);

    // ---- O = P V (V^T frags from L2) ----
    f32x4 oa[4][5] = {};
    {
        f16x8 bv[15];
        const ushort* Vbase = Vt_g + (size_t)(b*8 + w) * 7680;
#pragma unroll
        for (int ni = 0; ni < 5; ++ni)
#pragma unroll
            for (int kk = 0; kk < 3; ++kk)
                bv[ni*3+kk] = *(const f16x8*)(Vbase + (size_t)(ni*16 + l15)*96 + kk*32 + lhi*8);
#pragma unroll
        for (int kk = 0; kk < 3; ++kk) {
            f16x8 ap[4];
#pragma unroll
            for (int mi = 0; mi < 4; ++mi)
                ap[mi] = *(const f16x8*)&lds[qoff + (mi*16 + l15)*104 + kk*32 + lhi*8];
#pragma unroll
            for (int mi = 0; mi < 4; ++mi)
#pragma unroll
                for (int ni = 0; ni < 5; ++ni)
                    oa[mi][ni] = __builtin_amdgcn_mfma_f32_16x16x32_f16(ap[mi], bv[ni*3+kk], oa[mi][ni], 0, 0, 0);
        }
    }
    __syncthreads();   // everyone done with Qall/Ps before ctxall overwrites

    // ---- ctxall[64][648] = concat of heads ----
#pragma unroll
    for (int mi = 0; mi < 4; ++mi)
#pragma unroll
        for (int ni = 0; ni < 5; ++ni)
#pragma unroll
            for (int r = 0; r < 4; ++r)
                lds[(mi*16 + lhi*4 + r)*648 + w*80 + ni*16 + l15] = f2h(oa[mi][ni][r]);
    __syncthreads();

    // ---- O projection: out = ctxall @ Wo[:, w*80..+80] + bo ----
    f32x4 cacc[4][5] = {};
    const ushort* Orow = WoT + (size_t)(w * 80) * 640;
#pragma unroll
    for (int ni = 0; ni < 5; ++ni)
#pragma unroll
        for (int kk = 0; kk < 2; ++kk)
            BbE[ni*2+kk] = *(const f16x8*)(Orow + (size_t)(ni*16 + l15)*640 + kk*32 + lhi*8);
#define OSTEP(BCUR, BNXT, KT) do { \
    const int kt_ = (KT); \
    if (kt_ < 9) { \
        _Pragma("unroll") for (int ni = 0; ni < 5; ++ni) \
        _Pragma("unroll") for (int kk = 0; kk < 2; ++kk) \
            (BNXT)[ni*2+kk] = *(const f16x8*)(Orow + (size_t)(ni*16+l15)*640 + (kt_+1)*64 + kk*32 + lhi*8); \
    } \
    _Pragma("unroll") for (int kk = 0; kk < 2; ++kk) { \
        f16x8 af[4]; \
        _Pragma("unroll") for (int mi = 0; mi < 4; ++mi) \
            af[mi] = *(const f16x8*)&lds[(mi*16 + l15)*648 + kt_*64 + kk*32 + lhi*8]; \
        _Pragma("unroll") for (int mi = 0; mi < 4; ++mi) \
        _Pragma("unroll") for (int ni = 0; ni < 5; ++ni) \
            cacc[mi][ni] = __builtin_amdgcn_mfma_f32_16x16x32_f16(af[mi], (BCUR)[ni*2+kk], cacc[mi][ni], 0, 0, 0); \
    } \
} while (0)
    for (int kp = 0; kp < 5; ++kp) {
        OSTEP(BbE, BbO, 2*kp);
        OSTEP(BbO, BbE, 2*kp + 1);
    }
#undef OSTEP

    // ---- epilogue: f32 out + bias ----
#pragma unroll
    for (int ni = 0; ni < 5; ++ni) {
        int col = w*80 + ni*16 + l15;
        float bvl = bo[col];
#pragma unroll
        for (int mi = 0; mi < 4; ++mi)
#pragma unroll
            for (int r = 0; r < 4; ++r)
                out[(rowbase + mi*16 + lhi*4 + r) * 640 + col] = cacc[mi][ni][r] + bvl;
    }
}

extern "C" void kernel_launch(void* const* d_in, const int* in_sizes, int n_in,
                              void* d_out, int out_size, void* d_ws, size_t ws_size,
                              hipStream_t stream) {
    (void)in_sizes; (void)n_in; (void)out_size; (void)ws_size;
    const float* tokens  = (const float*)d_in[0];
    const float* context = (const float*)d_in[1];
    const float* Wq = (const float*)d_in[2];
    const float* Wk = (const float*)d_in[3];
    const float* Wv = (const float*)d_in[4];
    const float* Wo = (const float*)d_in[5];
    const float* bo = (const float*)d_in[6];
    float* out = (float*)d_out;

    ushort* ws   = (ushort*)d_ws;
    ushort* ctx16 = ws;                                   // 616*768   = 473,088
    ushort* WqT  = ctx16 + (size_t)616 * 768;             // 640*640
    ushort* WoT  = WqT  + (size_t)640 * 640;              // 640*640
    ushort* WkvT = WoT  + (size_t)640 * 640;              // 1280*768
    ushort* KVb  = WkvT + (size_t)1280 * 768;             // 616*1280
    ushort* Vt_g = KVb  + (size_t)616 * 1280;             // 64*80*96

    cvt_kernel<<<462, 256, 0, stream>>>(context, ctx16, 616 * 768 / 4);
    transpose_cvt<<<dim3(20, 20), dim3(32, 8), 0, stream>>>(Wq, WqT, 640, 640);
    transpose_cvt<<<dim3(20, 20), dim3(32, 8), 0, stream>>>(Wo, WoT, 640, 640);
    transpose_cvt<<<dim3(20, 24), dim3(32, 8), 0, stream>>>(Wk, WkvT, 768, 640);
    transpose_cvt<<<dim3(20, 24), dim3(32, 8), 0, stream>>>(Wv, WkvT + (size_t)640 * 768, 768, 640);

    gemm_bt<1, 0><<<dim3(5, 10), 256, 0, stream>>>(ctx16, WkvT, KVb, nullptr, 616, 1280, 768);
    vtrans_kernel<<<64, 256, 0, stream>>>(KVb, Vt_g);
    fused_attn<<<dim3(64, 8), 512, 0, stream>>>(tokens, WqT, KVb, Vt_g, WoT, bo, out);
}